// Round 1
// baseline (287.598 us; speedup 1.0000x reference)
//
#include <hip/hip_runtime.h>

// Problem constants (match reference)
#define N_EDGES 800000
#define D 64  // D_FEAT == EDGE_DIM == 64, K = 2*D = 128

typedef __attribute__((ext_vector_type(8))) short bf16x8;  // 8 bf16 in 4 VGPRs
typedef __attribute__((ext_vector_type(4))) float f32x4;   // MFMA accumulator

// f32 -> bf16 round-to-nearest-even (inputs are finite, skip NaN path)
__device__ __forceinline__ short f2bf(float f) {
    unsigned int u = __float_as_uint(f);
    u += 0x7fffu + ((u >> 16) & 1u);
    return (short)(u >> 16);
}

// One wave handles 64 edges (4 m-tiles of 16). Block = 4 waves = 256 edges.
// GEMM: out[e][n] = tanh( sum_k feats[e][k] * W[k][n] + b[n] ),
//   feats[e][0:64]  = node_feats[receivers[e]]
//   feats[e][64:128]= node_feats[senders[e]]
__global__ __launch_bounds__(256) void edge_mlp(
    const float* __restrict__ node_feats,
    const int*   __restrict__ senders,
    const int*   __restrict__ receivers,
    const float* __restrict__ W,      // [128][64] row-major
    const float* __restrict__ bias,   // [64]
    float*       __restrict__ out)    // [N_EDGES][64]
{
    const int lane = threadIdx.x & 63;
    const int m    = lane & 15;   // edge-within-tile (A row, B col, C col)
    const int q    = lane >> 4;   // quad: k-slice owner / C row group
    const long wid = (long)blockIdx.x * 4 + (threadIdx.x >> 6);
    const long e0  = wid * 64;
    if (e0 >= N_EDGES) return;    // exact divide (800000/64=12500), kept for safety

    // Edge endpoint indices: nidx[0]=receivers (k<64), nidx[1]=senders (k>=64)
    int nidx[2][4];
#pragma unroll
    for (int mt = 0; mt < 4; ++mt) {
        const long e = e0 + mt * 16 + m;
        nidx[0][mt] = receivers[e];
        nidx[1][mt] = senders[e];
    }

    f32x4 acc[4][4];
#pragma unroll
    for (int mt = 0; mt < 4; ++mt)
#pragma unroll
        for (int nt = 0; nt < 4; ++nt)
            acc[mt][nt] = (f32x4)0.0f;

#pragma unroll
    for (int ki = 0; ki < 4; ++ki) {          // K = 128 in 4 slices of 32
        const int k0 = ki * 32 + q * 8;       // this lane's 8 k's: k0..k0+7

        // B fragments: lane holds W[k0+j][nt*16+m], j=0..7.
        // W is 32KB, L1-resident; addresses = one base + imm offsets.
        bf16x8 bfrag[4];
        const float* wp = W + (long)k0 * D + m;
#pragma unroll
        for (int nt = 0; nt < 4; ++nt) {
#pragma unroll
            for (int j = 0; j < 8; ++j)
                bfrag[nt][j] = f2bf(wp[j * D + nt * 16]);
        }

#pragma unroll
        for (int mt = 0; mt < 4; ++mt) {
            // Gather: 8 consecutive f32 (32B, 16B-aligned) from the node row
            const int node = nidx[ki >> 1][mt];   // ki 0,1 -> recv; 2,3 -> send
            const float* fp = node_feats + (long)node * D + (k0 & 63);
            const float4 lo = *(const float4*)fp;
            const float4 hi = *(const float4*)(fp + 4);
            bf16x8 afrag;
            afrag[0] = f2bf(lo.x); afrag[1] = f2bf(lo.y);
            afrag[2] = f2bf(lo.z); afrag[3] = f2bf(lo.w);
            afrag[4] = f2bf(hi.x); afrag[5] = f2bf(hi.y);
            afrag[6] = f2bf(hi.z); afrag[7] = f2bf(hi.w);
#pragma unroll
            for (int nt = 0; nt < 4; ++nt)
                acc[mt][nt] = __builtin_amdgcn_mfma_f32_16x16x32_bf16(
                    afrag, bfrag[nt], acc[mt][nt], 0, 0, 0);
        }
    }

    // Epilogue: C/D layout col = m, row = q*4 + r.
    float bv[4];
#pragma unroll
    for (int nt = 0; nt < 4; ++nt) bv[nt] = bias[nt * 16 + m];

#pragma unroll
    for (int mt = 0; mt < 4; ++mt) {
#pragma unroll
        for (int r = 0; r < 4; ++r) {
            const long row = e0 + mt * 16 + q * 4 + r;
            float* op = out + row * D + m;
#pragma unroll
            for (int nt = 0; nt < 4; ++nt) {
                const float x  = acc[mt][nt][r] + bv[nt];
                const float ax = __builtin_fabsf(x);
                const float t  = __expf(-2.0f * ax);          // in (0,1]: no overflow
                float y = (1.0f - t) * __builtin_amdgcn_rcpf(1.0f + t);
                y = __builtin_copysignf(y, x);
                __builtin_nontemporal_store(y, op + nt * 16); // out never re-read
            }
        }
    }
}

extern "C" void kernel_launch(void* const* d_in, const int* in_sizes, int n_in,
                              void* d_out, int out_size, void* d_ws, size_t ws_size,
                              hipStream_t stream) {
    const float* node_feats = (const float*)d_in[0];
    const int*   senders    = (const int*)d_in[1];
    const int*   receivers  = (const int*)d_in[2];
    const float* W          = (const float*)d_in[3];
    const float* bias       = (const float*)d_in[4];
    float*       out        = (float*)d_out;

    // 256 threads = 4 waves, 64 edges/wave -> 256 edges/block; 800000/256 = 3125
    const int n_blocks = (N_EDGES + 255) / 256;
    edge_mlp<<<n_blocks, 256, 0, stream>>>(node_feats, senders, receivers, W, bias, out);
}

// Round 2
// 274.271 us; speedup vs baseline: 1.0486x; 1.0486x over previous
//
#include <hip/hip_runtime.h>

#define N_EDGES 800000
#define N_NODES 50000
#define D 64                 // D_FEAT == EDGE_DIM == 64, K = 2*D = 128
#define WT_STRIDE 136        // bf16 elements per WT row (128 + 8 pad)

typedef __attribute__((ext_vector_type(8))) short bf16x8;  // 8 bf16 = 16 B
typedef __attribute__((ext_vector_type(4))) float f32x4;   // MFMA accumulator

// f32 -> bf16 round-to-nearest-even (finite inputs)
__device__ __forceinline__ unsigned short f2bf(float f) {
    unsigned int u = __float_as_uint(f);
    u += 0x7fffu + ((u >> 16) & 1u);
    return (unsigned short)(u >> 16);
}
__device__ __forceinline__ unsigned int pack2(float a, float b) {
    return (unsigned int)f2bf(a) | ((unsigned int)f2bf(b) << 16);
}

// Prep: convert node_feats (50000x64 f32) -> bf16 table; W (128x64 f32) ->
// transposed bf16 WT[64][WT_STRIDE]. Runs every call (graph-safe, ws is
// re-poisoned each iteration).
__global__ __launch_bounds__(256) void prep(
    const float* __restrict__ nf, const float* __restrict__ W,
    unsigned short* __restrict__ nodes_bf, unsigned short* __restrict__ wt_bf)
{
    if (blockIdx.x == gridDim.x - 1) {
        // WT[n][k] = bf16(W[k][n]); contiguous bf16 writes, strided f32 reads (16 KB total)
        for (int i = threadIdx.x; i < D * 128; i += 256) {
            const int n = i >> 7, k = i & 127;
            wt_bf[n * WT_STRIDE + k] = f2bf(W[k * D + n]);
        }
    } else {
        const long base = ((long)blockIdx.x * 256 + threadIdx.x) * 8;
        if (base < (long)N_NODES * D) {
            const float4 lo = *(const float4*)(nf + base);
            const float4 hi = *(const float4*)(nf + base + 4);
            uint4 p;
            p.x = pack2(lo.x, lo.y);
            p.y = pack2(lo.z, lo.w);
            p.z = pack2(hi.x, hi.y);
            p.w = pack2(hi.z, hi.w);
            *(uint4*)(nodes_bf + base) = p;
        }
    }
}

// One wave = 64 edges (4 m-tiles of 16). Block = 4 waves = 256 edges.
// out[e][n] = tanh( sum_k feats[e][k] * W[k][n] + b[n] ),
//   feats[e][0:64] = nodes_bf[receivers[e]], feats[e][64:128] = nodes_bf[senders[e]]
__global__ __launch_bounds__(256) void edge_mlp(
    const unsigned short* __restrict__ nodes_bf,  // [N_NODES][64] bf16
    const unsigned short* __restrict__ wt_bf,     // [64][WT_STRIDE] bf16, WT[n][k]=W[k][n]
    const int*   __restrict__ senders,
    const int*   __restrict__ receivers,
    const float* __restrict__ bias,
    float*       __restrict__ out)                // [N_EDGES][64] f32
{
    const int lane = threadIdx.x & 63;
    const int m    = lane & 15;   // A row / B col / C col
    const int q    = lane >> 4;   // quad: k-slice owner / C row group
    const long wid = (long)blockIdx.x * 4 + (threadIdx.x >> 6);
    const long e0  = wid * 64;
    if (e0 >= N_EDGES) return;

    // Endpoint indices: [0]=receivers (k<64), [1]=senders (k>=64)
    int nidx[2][4];
#pragma unroll
    for (int mt = 0; mt < 4; ++mt) {
        const long e = e0 + mt * 16 + m;
        nidx[0][mt] = receivers[e];
        nidx[1][mt] = senders[e];
    }

    f32x4 acc[4][4];
#pragma unroll
    for (int mt = 0; mt < 4; ++mt)
#pragma unroll
        for (int nt = 0; nt < 4; ++nt)
            acc[mt][nt] = (f32x4)0.0f;

#pragma unroll
    for (int ki = 0; ki < 4; ++ki) {           // K = 128 in 4 slices of 32
        const int k0 = ki * 32 + q * 8;        // this lane's 8 k's

        // B fragments: one 16 B load per nt from the transposed bf16 W (L2-resident)
        bf16x8 bfrag[4];
#pragma unroll
        for (int nt = 0; nt < 4; ++nt)
            bfrag[nt] = *(const bf16x8*)(wt_bf + (nt * 16 + m) * WT_STRIDE + k0);

        // A fragments: one 16 B gather per mt from the bf16 node row
        bf16x8 afrag[4];
#pragma unroll
        for (int mt = 0; mt < 4; ++mt) {
            const int node = nidx[ki >> 1][mt];   // ki 0,1 -> recv; 2,3 -> send
            afrag[mt] = *(const bf16x8*)(nodes_bf + node * D + (k0 & 63));
        }

#pragma unroll
        for (int mt = 0; mt < 4; ++mt)
#pragma unroll
            for (int nt = 0; nt < 4; ++nt)
                acc[mt][nt] = __builtin_amdgcn_mfma_f32_16x16x32_bf16(
                    afrag[mt], bfrag[nt], acc[mt][nt], 0, 0, 0);
    }

    // Epilogue: C/D layout col = m, row = q*4 + r
    float bv[4];
#pragma unroll
    for (int nt = 0; nt < 4; ++nt) bv[nt] = bias[nt * 16 + m];

#pragma unroll
    for (int mt = 0; mt < 4; ++mt) {
#pragma unroll
        for (int r = 0; r < 4; ++r) {
            const long row = e0 + mt * 16 + q * 4 + r;
            float* op = out + row * D + m;
#pragma unroll
            for (int nt = 0; nt < 4; ++nt) {
                const float x  = acc[mt][nt][r] + bv[nt];
                const float ax = __builtin_fabsf(x);
                const float t  = __expf(-2.0f * ax);           // (0,1]: no overflow
                float y = (1.0f - t) * __builtin_amdgcn_rcpf(1.0f + t);
                y = __builtin_copysignf(y, x);
                __builtin_nontemporal_store(y, op + nt * 16);  // out never re-read
            }
        }
    }
}

extern "C" void kernel_launch(void* const* d_in, const int* in_sizes, int n_in,
                              void* d_out, int out_size, void* d_ws, size_t ws_size,
                              hipStream_t stream) {
    const float* node_feats = (const float*)d_in[0];
    const int*   senders    = (const int*)d_in[1];
    const int*   receivers  = (const int*)d_in[2];
    const float* W          = (const float*)d_in[3];
    const float* bias       = (const float*)d_in[4];
    float*       out        = (float*)d_out;

    // ws layout: [0, 6.4MB) bf16 node table; then WT (64*136*2 = 17408 B)
    unsigned short* nodes_bf = (unsigned short*)d_ws;
    unsigned short* wt_bf    = (unsigned short*)((char*)d_ws + (size_t)N_NODES * D * 2);

    // prep: 1563 node blocks (ceil(3.2M/2048)) + 1 W block
    const int node_blocks = ((N_NODES * D / 8) + 255) / 256;
    prep<<<node_blocks + 1, 256, 0, stream>>>(node_feats, W, nodes_bf, wt_bf);

    const int n_blocks = (N_EDGES + 255) / 256;  // 4 waves/block, 64 edges/wave
    edge_mlp<<<n_blocks, 256, 0, stream>>>(nodes_bf, wt_bf, senders, receivers, bias, out);
}

// Round 3
// 257.236 us; speedup vs baseline: 1.1180x; 1.0662x over previous
//
#include <hip/hip_runtime.h>

#define N_EDGES 800000
#define N_NODES 50000
#define D 64                 // D_FEAT == EDGE_DIM == 64, K = 2*D = 128

typedef __attribute__((ext_vector_type(8))) short bf16x8;  // 8 bf16 = 16 B
typedef __attribute__((ext_vector_type(4))) float f32x4;   // MFMA accumulator

// f32 -> bf16 round-to-nearest-even (finite inputs)
__device__ __forceinline__ unsigned short f2bf(float f) {
    unsigned int u = __float_as_uint(f);
    u += 0x7fffu + ((u >> 16) & 1u);
    return (unsigned short)(u >> 16);
}
__device__ __forceinline__ unsigned int pack2(float a, float b) {
    return (unsigned int)f2bf(a) | ((unsigned int)f2bf(b) << 16);
}

// Prep (runs every call; ws re-poisoned each iter):
//  (a) node_feats (50000x64 f32) -> bf16 table (6.4 MB)
//  (b) W (128x64 f32) -> per-lane MFMA B-fragment order: 1024 x 16B entries.
//      entry idx = (ki*4+nt)*64 + l, l = q*16+m:
//      frag[j] = bf16(W[ki*32+q*8+j][nt*16+m]), j=0..7
__global__ __launch_bounds__(256) void prep(
    const float* __restrict__ nf, const float* __restrict__ W,
    unsigned short* __restrict__ nodes_bf, unsigned short* __restrict__ wfrag)
{
    if (blockIdx.x == gridDim.x - 1) {
#pragma unroll
        for (int i = 0; i < 4; ++i) {
            const int idx = i * 256 + threadIdx.x;     // 0..1023
            const int ki = idx >> 8;
            const int nt = (idx >> 6) & 3;
            const int l  = idx & 63;
            const int m  = l & 15, q = l >> 4;
            const int kbase = ki * 32 + q * 8;
            const int n = nt * 16 + m;
            unsigned short* dst = wfrag + idx * 8;
#pragma unroll
            for (int j = 0; j < 8; ++j)
                dst[j] = f2bf(W[(kbase + j) * D + n]);
        }
    } else {
        const long base = ((long)blockIdx.x * 256 + threadIdx.x) * 8;
        if (base < (long)N_NODES * D) {
            const float4 lo = *(const float4*)(nf + base);
            const float4 hi = *(const float4*)(nf + base + 4);
            uint4 p;
            p.x = pack2(lo.x, lo.y);
            p.y = pack2(lo.z, lo.w);
            p.z = pack2(hi.x, hi.y);
            p.w = pack2(hi.z, hi.w);
            *(uint4*)(nodes_bf + base) = p;
        }
    }
}

// One wave = 64 edges (4 m-tiles of 16). Block = 4 waves = 256 edges.
// out[e][n] = tanh( sum_k feats[e][k] * W[k][n] + b[n] )
__global__ __launch_bounds__(256) void edge_mlp(
    const unsigned short* __restrict__ nodes_bf,  // [N_NODES][64] bf16
    const bf16x8*        __restrict__ wfrag,      // [1024] B-fragments, 16 KB
    const int*   __restrict__ senders,
    const int*   __restrict__ receivers,
    const float* __restrict__ bias,
    float*       __restrict__ out)                // [N_EDGES][64] f32
{
    __shared__ bf16x8 lds_b[1024];                // 16 KB, fragment order

    // Stage B-fragments: 4 fully-coalesced 16B/lane loads, lane-contiguous
    // ds_write/ds_read (2-way aliasing only -> conflict-free on gfx950).
#pragma unroll
    for (int i = 0; i < 4; ++i) {
        const int idx = i * 256 + threadIdx.x;
        lds_b[idx] = wfrag[idx];
    }
    __syncthreads();

    const int lane = threadIdx.x & 63;
    const int m    = lane & 15;   // A row / B col / C col
    const int q    = lane >> 4;   // quad: k-slice owner / C row group
    const long wid = (long)blockIdx.x * 4 + (threadIdx.x >> 6);
    const long e0  = wid * 64;    // grid is exact: 800000/64 waves

    // Indices: 2 lane-contiguous loads + shuffle distribution
    const int rv = receivers[e0 + lane];
    const int sv = senders[e0 + lane];
    int nidx[2][4];
#pragma unroll
    for (int mt = 0; mt < 4; ++mt) {
        nidx[0][mt] = __shfl(rv, mt * 16 + m, 64);
        nidx[1][mt] = __shfl(sv, mt * 16 + m, 64);
    }

    f32x4 acc[4][4];
#pragma unroll
    for (int mt = 0; mt < 4; ++mt)
#pragma unroll
        for (int nt = 0; nt < 4; ++nt)
            acc[mt][nt] = (f32x4)0.0f;

#pragma unroll
    for (int ki = 0; ki < 4; ++ki) {           // K = 128 in 4 slices of 32
        const int k0 = ki * 32 + q * 8;

        // B fragments from LDS (pre-swizzled, lane-contiguous)
        bf16x8 bfrag[4];
#pragma unroll
        for (int nt = 0; nt < 4; ++nt)
            bfrag[nt] = lds_b[(ki * 4 + nt) * 64 + lane];

        // A fragments: one 16B gather per mt from the bf16 node row
        bf16x8 afrag[4];
#pragma unroll
        for (int mt = 0; mt < 4; ++mt) {
            const int node = nidx[ki >> 1][mt];   // ki 0,1 -> recv; 2,3 -> send
            afrag[mt] = *(const bf16x8*)(nodes_bf + node * D + (k0 & 63));
        }

#pragma unroll
        for (int mt = 0; mt < 4; ++mt)
#pragma unroll
            for (int nt = 0; nt < 4; ++nt)
                acc[mt][nt] = __builtin_amdgcn_mfma_f32_16x16x32_bf16(
                    afrag[mt], bfrag[nt], acc[mt][nt], 0, 0, 0);
    }

    // Epilogue: C/D layout col = m, row = q*4 + r
    float bv[4];
#pragma unroll
    for (int nt = 0; nt < 4; ++nt) bv[nt] = bias[nt * 16 + m];

#pragma unroll
    for (int mt = 0; mt < 4; ++mt) {
#pragma unroll
        for (int r = 0; r < 4; ++r) {
            const long row = e0 + mt * 16 + q * 4 + r;
            float* op = out + row * D + m;
#pragma unroll
            for (int nt = 0; nt < 4; ++nt) {
                const float x  = acc[mt][nt][r] + bv[nt];
                const float ax = __builtin_fabsf(x);
                const float t  = __expf(-2.0f * ax);           // (0,1]: no overflow
                float y = (1.0f - t) * __builtin_amdgcn_rcpf(1.0f + t);
                y = __builtin_copysignf(y, x);
                __builtin_nontemporal_store(y, op + nt * 16);  // out never re-read
            }
        }
    }
}

extern "C" void kernel_launch(void* const* d_in, const int* in_sizes, int n_in,
                              void* d_out, int out_size, void* d_ws, size_t ws_size,
                              hipStream_t stream) {
    const float* node_feats = (const float*)d_in[0];
    const int*   senders    = (const int*)d_in[1];
    const int*   receivers  = (const int*)d_in[2];
    const float* W          = (const float*)d_in[3];
    const float* bias       = (const float*)d_in[4];
    float*       out        = (float*)d_out;

    // ws layout: [0, 6.4MB) bf16 node table (16B-aligned); then wfrag 16 KB
    unsigned short* nodes_bf = (unsigned short*)d_ws;
    unsigned short* wfrag    = (unsigned short*)((char*)d_ws + (size_t)N_NODES * D * 2);

    const int node_blocks = ((N_NODES * D / 8) + 255) / 256;   // 1563
    prep<<<node_blocks + 1, 256, 0, stream>>>(node_feats, W, nodes_bf, wfrag);

    const int n_blocks = N_EDGES / 256;   // 3125 exact: 4 waves/block, 64 edges/wave
    edge_mlp<<<n_blocks, 256, 0, stream>>>(nodes_bf, (const bf16x8*)wfrag,
                                           senders, receivers, bias, out);
}